// Round 1
// baseline (8476.846 us; speedup 1.0000x reference)
//
#include <hip/hip_runtime.h>
#include <hip/hip_bf16.h>

typedef unsigned int  u32;
typedef unsigned short u16;

#define B_   1024
#define T_   128
#define NBT  (B_*T_)

__device__ __forceinline__ float bf_lo(u32 u){ return __uint_as_float(u << 16); }
__device__ __forceinline__ float bf_hi(u32 u){ return __uint_as_float(u & 0xffff0000u); }
__device__ __forceinline__ u16 f2bf(float f){
  u32 u = __float_as_uint(f);
  u32 r = u + 0x7fffu + ((u >> 16) & 1u);   // round-to-nearest-even
  return (u16)(r >> 16);
}

// ---------------------------------------------------------------------------
// K1: per-sample feature pipeline, 8 samples / 256-thread block.
// states[94] -> conv1(16ch 3x3 SAME on 7x10) -> conv2(32ch) -> grid_fc(128)
//            -> ctx_fc(64) -> trunk(128) -> gates_x[512] (+b_ih), fp32 in LDS.
// Writes gates_x layout [t][b][512] (t = n & 127, b = n >> 7).
// ---------------------------------------------------------------------------
template<int USE_BF16>
__global__ __launch_bounds__(256, 1) void k_features(
    const float* __restrict__ states,
    const float* __restrict__ c1w, const float* __restrict__ c1b,
    const float* __restrict__ c2w, const float* __restrict__ c2b,
    const float* __restrict__ gfw, const float* __restrict__ gfb,
    const float* __restrict__ cfw, const float* __restrict__ cfb,
    const float* __restrict__ tw,  const float* __restrict__ tbv,
    const float* __restrict__ wih, const float* __restrict__ bih,
    void* __restrict__ gates_out)
{
  __shared__ float s_st[8][96];        // 3.0 KB  raw state (94 used)
  __shared__ float s_c1[8][16][70];    // 35.8 KB conv1 out (relu)
  __shared__ float s_c2[8][2240];      // 71.7 KB conv2 out (relu, flat ch*70+p)
  __shared__ float s_w1[144];
  __shared__ float s_w2[32][16][9];    // 18.4 KB
  __shared__ float s_go[8][128];       // grid_fc out
  __shared__ float s_co[8][64];        // ctx_fc out
  __shared__ float s_to[8][128];       // trunk out
  __shared__ float s_gp[8][128];       // k-split partial

  const int tid = threadIdx.x;
  const int n0  = blockIdx.x * 8;

  // ---- stage states + conv weights ----
  for (int i = tid; i < 8*94; i += 256) s_st[i/94][i%94] = states[(size_t)n0*94 + i];
  for (int i = tid; i < 144;  i += 256) s_w1[i] = c1w[i];
  for (int i = tid; i < 4608; i += 256) ((float*)s_w2)[i] = c2w[i];
  __syncthreads();

  // ---- conv1: 8*16*70 = 8960 outputs ----
  for (int idx = tid; idx < 8960; idx += 256) {
    int s = idx / 1120; int r = idx - s*1120;
    int ch = r / 70;    int p = r - ch*70;
    int y = p / 10, x = p - y*10;
    float acc = c1b[ch];
    #pragma unroll
    for (int dy = 0; dy < 3; dy++) {
      int yy = y + dy - 1;
      if (yy < 0 || yy >= 7) continue;
      #pragma unroll
      for (int dx = 0; dx < 3; dx++) {
        int xx = x + dx - 1;
        if (xx < 0 || xx >= 10) continue;
        acc = fmaf(s_w1[ch*9 + dy*3 + dx], s_st[s][yy*10 + xx], acc);
      }
    }
    s_c1[s][ch][p] = fmaxf(acc, 0.f);
  }
  __syncthreads();

  // ---- conv2: row tasks, 8*32*7 = 1792 (=7*256) ----
  for (int task = tid; task < 1792; task += 256) {
    int s = task / 224; int r = task - s*224;
    int ch = r / 7;     int y = r - ch*7;
    float bias = c2b[ch];
    float acc[10];
    #pragma unroll
    for (int x = 0; x < 10; x++) acc[x] = bias;
    for (int ci = 0; ci < 16; ci++) {
      float row[3][12];
      #pragma unroll
      for (int dy = 0; dy < 3; dy++) {
        int yy = y + dy - 1;
        row[dy][0] = 0.f; row[dy][11] = 0.f;
        if (yy >= 0 && yy < 7) {
          #pragma unroll
          for (int x = 0; x < 10; x++) row[dy][x+1] = s_c1[s][ci][yy*10 + x];
        } else {
          #pragma unroll
          for (int x = 0; x < 10; x++) row[dy][x+1] = 0.f;
        }
      }
      float w[9];
      #pragma unroll
      for (int j = 0; j < 9; j++) w[j] = s_w2[ch][ci][j];
      #pragma unroll
      for (int x = 0; x < 10; x++) {
        float a = acc[x];
        a = fmaf(w[0], row[0][x], a); a = fmaf(w[1], row[0][x+1], a); a = fmaf(w[2], row[0][x+2], a);
        a = fmaf(w[3], row[1][x], a); a = fmaf(w[4], row[1][x+1], a); a = fmaf(w[5], row[1][x+2], a);
        a = fmaf(w[6], row[2][x], a); a = fmaf(w[7], row[2][x+1], a); a = fmaf(w[8], row[2][x+2], a);
        acc[x] = a;
      }
    }
    int pb = ch*70 + y*10;
    #pragma unroll
    for (int x = 0; x < 10; x++) s_c2[s][pb + x] = fmaxf(acc[x], 0.f);
  }
  __syncthreads();

  // ---- grid_fc: out[8][128], K=2240 split across thread halves ----
  {
    const int o = tid & 127; const int half = tid >> 7;
    const int kb = half * 1120;
    float acc[8] = {0,0,0,0,0,0,0,0};
    const float* wr = gfw + (size_t)o*2240 + kb;
    for (int k = 0; k < 1120; k += 4) {
      float4 w4 = *(const float4*)(wr + k);
      #pragma unroll
      for (int s = 0; s < 8; s++) {
        float4 c4 = *(const float4*)&s_c2[s][kb + k];
        float a = acc[s];
        a = fmaf(w4.x, c4.x, a); a = fmaf(w4.y, c4.y, a);
        a = fmaf(w4.z, c4.z, a); a = fmaf(w4.w, c4.w, a);
        acc[s] = a;
      }
    }
    if (half == 1) {
      #pragma unroll
      for (int s = 0; s < 8; s++) s_gp[s][o] = acc[s];
    }
    __syncthreads();
    if (half == 0) {
      float bv = gfb[o];
      #pragma unroll
      for (int s = 0; s < 8; s++) s_go[s][o] = fmaxf(acc[s] + s_gp[s][o] + bv, 0.f);
    } else {
      // ctx_fc: 8*64 outputs by the other 128 threads (4 samples each)
      int t2 = tid - 128; int o2 = t2 & 63; int sh = (t2 >> 6) * 4;
      float bv = cfb[o2];
      for (int si = 0; si < 4; si++) {
        int s = sh + si;
        float a = bv;
        #pragma unroll
        for (int k = 0; k < 24; k++) a = fmaf(cfw[o2*24 + k], s_st[s][70 + k], a);
        s_co[s][o2] = fmaxf(a, 0.f);
      }
    }
  }
  __syncthreads();

  // ---- trunk: out[8][128], K=192 split 96/96 ----
  {
    const int o = tid & 127; const int half = tid >> 7;
    const int kb = half * 96;
    float acc[8] = {0,0,0,0,0,0,0,0};
    const float* wr = tw + (size_t)o*192 + kb;
    for (int k = 0; k < 96; k++) {
      float wv = wr[k];
      int kk = kb + k;
      if (kk < 128) {
        #pragma unroll
        for (int s = 0; s < 8; s++) acc[s] = fmaf(wv, s_go[s][kk], acc[s]);
      } else {
        #pragma unroll
        for (int s = 0; s < 8; s++) acc[s] = fmaf(wv, s_co[s][kk - 128], acc[s]);
      }
    }
    if (half == 1) {
      #pragma unroll
      for (int s = 0; s < 8; s++) s_gp[s][o] = acc[s];
    }
    __syncthreads();
    if (half == 0) {
      float bv = tbv[o];
      #pragma unroll
      for (int s = 0; s < 8; s++) s_to[s][o] = fmaxf(acc[s] + s_gp[s][o] + bv, 0.f);
    }
  }
  __syncthreads();

  // ---- gates_x: g = tid and tid+256 (512 gates), K=128 ----
  {
    float acc0[8] = {0,0,0,0,0,0,0,0};
    float acc1[8] = {0,0,0,0,0,0,0,0};
    const float* w0 = wih + (size_t)tid * 128;
    const float* w1 = wih + (size_t)(tid + 256) * 128;
    for (int k = 0; k < 128; k += 4) {
      float4 a4 = *(const float4*)(w0 + k);
      float4 b4 = *(const float4*)(w1 + k);
      #pragma unroll
      for (int s = 0; s < 8; s++) {
        float4 t4 = *(const float4*)&s_to[s][k];
        float x0 = acc0[s], x1 = acc1[s];
        x0 = fmaf(a4.x, t4.x, x0); x0 = fmaf(a4.y, t4.y, x0);
        x0 = fmaf(a4.z, t4.z, x0); x0 = fmaf(a4.w, t4.w, x0);
        x1 = fmaf(b4.x, t4.x, x1); x1 = fmaf(b4.y, t4.y, x1);
        x1 = fmaf(b4.z, t4.z, x1); x1 = fmaf(b4.w, t4.w, x1);
        acc0[s] = x0; acc1[s] = x1;
      }
    }
    float bi0 = bih[tid], bi1 = bih[tid + 256];
    for (int s = 0; s < 8; s++) {
      int n = n0 + s; int tt = n & 127; int bb = n >> 7;
      size_t base = ((size_t)tt * B_ + bb) * 512;
      float v0 = acc0[s] + bi0, v1 = acc1[s] + bi1;
      if (USE_BF16) {
        ((u16*)gates_out)[base + tid]       = f2bf(v0);
        ((u16*)gates_out)[base + tid + 256] = f2bf(v1);
      } else {
        ((float*)gates_out)[base + tid]       = v0;
        ((float*)gates_out)[base + tid + 256] = v1;
      }
    }
  }
}

// ---------------------------------------------------------------------------
// K2: LSTM over T=128 + fused heads. 256 blocks x 256 threads; each block
// owns 4 batch rows end-to-end (batch rows are independent -> no grid sync).
// W_hh^T in LDS as bf16 (128 KB), fp32 accumulate.
// ---------------------------------------------------------------------------
template<int USE_BF16>
__global__ __launch_bounds__(256, 1) void k_lstm(
    const void* __restrict__ gates_x, const float* __restrict__ whh,
    const int* __restrict__ actions,
    const float* __restrict__ aw, const float* __restrict__ ab,
    const float* __restrict__ cw, const float* __restrict__ cb,
    float* __restrict__ out)
{
  __shared__ u16   s_WT[128][512];   // 128 KB, WT[k][g] = W_hh[g][k]
  __shared__ float s_h[4][128];
  __shared__ float s_g[4][512];

  const int tid = threadIdx.x;
  const int b0  = blockIdx.x * 4;

  for (int i = tid; i < 512*128; i += 256) {
    int g = i >> 7, k = i & 127;
    s_WT[k][g] = f2bf(whh[i]);
  }
  for (int i = tid; i < 512; i += 256) s_h[i >> 7][i & 127] = 0.f;

  const int gb  = tid >> 6;           // batch slot for gate GEMM
  const int gg0 = (tid & 63) * 8;     // 8 consecutive gate outputs
  const int eb  = tid >> 6;           // batch slot for elementwise/heads
  const int eh  = tid & 63;

  float creg0 = 0.f, creg1 = 0.f;
  // hoist head weights (lane owns h-indices eh, eh+64)
  float haw[4][2], hcw[2];
  #pragma unroll
  for (int j = 0; j < 4; j++) { haw[j][0] = aw[j*128 + eh]; haw[j][1] = aw[j*128 + eh + 64]; }
  hcw[0] = cw[eh]; hcw[1] = cw[eh + 64];
  const float ab0 = ab[0], ab1 = ab[1], ab2 = ab[2], ab3 = ab[3], cb0 = cb[0];

  __syncthreads();

  for (int t = 0; t < T_; t++) {
    // ---- gates = gates_x[t][b] + h @ W_hh^T ----
    float acc[8];
    size_t gxoff = ((size_t)t * B_ + (b0 + gb)) * 512 + gg0;
    if (USE_BF16) {
      uint4 gv = *(const uint4*)((const u16*)gates_x + gxoff);
      acc[0]=bf_lo(gv.x); acc[1]=bf_hi(gv.x); acc[2]=bf_lo(gv.y); acc[3]=bf_hi(gv.y);
      acc[4]=bf_lo(gv.z); acc[5]=bf_hi(gv.z); acc[6]=bf_lo(gv.w); acc[7]=bf_hi(gv.w);
    } else {
      float4 g0 = *(const float4*)((const float*)gates_x + gxoff);
      float4 g1 = *(const float4*)((const float*)gates_x + gxoff + 4);
      acc[0]=g0.x; acc[1]=g0.y; acc[2]=g0.z; acc[3]=g0.w;
      acc[4]=g1.x; acc[5]=g1.y; acc[6]=g1.z; acc[7]=g1.w;
    }
    for (int k = 0; k < 128; k += 4) {
      float4 h4 = *(const float4*)&s_h[gb][k];
      #pragma unroll
      for (int j = 0; j < 4; j++) {
        float hv = (&h4.x)[j];
        uint4 wv = *(const uint4*)&s_WT[k + j][gg0];
        acc[0] = fmaf(bf_lo(wv.x), hv, acc[0]);
        acc[1] = fmaf(bf_hi(wv.x), hv, acc[1]);
        acc[2] = fmaf(bf_lo(wv.y), hv, acc[2]);
        acc[3] = fmaf(bf_hi(wv.y), hv, acc[3]);
        acc[4] = fmaf(bf_lo(wv.z), hv, acc[4]);
        acc[5] = fmaf(bf_hi(wv.z), hv, acc[5]);
        acc[6] = fmaf(bf_lo(wv.w), hv, acc[6]);
        acc[7] = fmaf(bf_hi(wv.w), hv, acc[7]);
      }
    }
    #pragma unroll
    for (int j = 0; j < 8; j++) s_g[gb][gg0 + j] = acc[j];
    __syncthreads();

    // ---- elementwise LSTM cell (thread owns (eb, eh) and (eb, eh+64)) ----
    float hn0, hn1;
    {
      float iv = s_g[eb][eh];
      float fv = s_g[eb][eh + 128];
      float gv = s_g[eb][eh + 256];
      float ov = s_g[eb][eh + 384];
      iv = 1.f / (1.f + __expf(-iv));
      fv = 1.f / (1.f + __expf(-fv));
      ov = 1.f / (1.f + __expf(-ov));
      gv = tanhf(gv);
      creg0 = fv * creg0 + iv * gv;
      hn0 = ov * tanhf(creg0);
      s_h[eb][eh] = hn0;
    }
    {
      float iv = s_g[eb][eh + 64];
      float fv = s_g[eb][eh + 64 + 128];
      float gv = s_g[eb][eh + 64 + 256];
      float ov = s_g[eb][eh + 64 + 384];
      iv = 1.f / (1.f + __expf(-iv));
      fv = 1.f / (1.f + __expf(-fv));
      ov = 1.f / (1.f + __expf(-ov));
      gv = tanhf(gv);
      creg1 = fv * creg1 + iv * gv;
      hn1 = ov * tanhf(creg1);
      s_h[eb][eh + 64] = hn1;
    }
    __syncthreads();

    // ---- heads: wave eb reduces over its 64 lanes ----
    float l0 = hn0*haw[0][0] + hn1*haw[0][1];
    float l1 = hn0*haw[1][0] + hn1*haw[1][1];
    float l2 = hn0*haw[2][0] + hn1*haw[2][1];
    float l3 = hn0*haw[3][0] + hn1*haw[3][1];
    float lv = hn0*hcw[0]    + hn1*hcw[1];
    #pragma unroll
    for (int off = 32; off; off >>= 1) {
      l0 += __shfl_xor(l0, off); l1 += __shfl_xor(l1, off);
      l2 += __shfl_xor(l2, off); l3 += __shfl_xor(l3, off);
      lv += __shfl_xor(lv, off);
    }
    if (eh == 0) {
      l0 += ab0; l1 += ab1; l2 += ab2; l3 += ab3; lv += cb0;
      float m  = fmaxf(fmaxf(l0, l1), fmaxf(l2, l3));
      float e0 = __expf(l0 - m), e1 = __expf(l1 - m), e2 = __expf(l2 - m), e3 = __expf(l3 - m);
      float S  = e0 + e1 + e2 + e3;
      float lse = __logf(S);
      float p0 = l0 - m - lse, p1 = l1 - m - lse, p2 = l2 - m - lse, p3 = l3 - m - lse;
      int n = (b0 + eb) * T_ + t;
      int a = actions[n];
      float lpa = (a == 0) ? p0 : (a == 1) ? p1 : (a == 2) ? p2 : p3;
      float ent = -(e0*p0 + e1*p1 + e2*p2 + e3*p3) / S;
      out[n]           = lpa;
      out[NBT + n]     = lv;
      out[2*NBT + n]   = ent;
    }
    // next iteration writes s_g only after the barrier above; s_h stable. OK.
  }
}

extern "C" void kernel_launch(void* const* d_in, const int* in_sizes, int n_in,
                              void* d_out, int out_size, void* d_ws, size_t ws_size,
                              hipStream_t stream) {
  const float* states = (const float*)d_in[0];
  const int*   actions= (const int*)  d_in[1];
  const float* c1w = (const float*)d_in[2];
  const float* c1b = (const float*)d_in[3];
  const float* c2w = (const float*)d_in[4];
  const float* c2b = (const float*)d_in[5];
  const float* gfw = (const float*)d_in[6];
  const float* gfb = (const float*)d_in[7];
  const float* cfw = (const float*)d_in[8];
  const float* cfb = (const float*)d_in[9];
  const float* tw  = (const float*)d_in[10];
  const float* tbv = (const float*)d_in[11];
  const float* wih = (const float*)d_in[12];
  const float* bih = (const float*)d_in[13];
  const float* whh = (const float*)d_in[14];
  const float* aw  = (const float*)d_in[15];
  const float* ab  = (const float*)d_in[16];
  const float* cw  = (const float*)d_in[17];
  const float* cb  = (const float*)d_in[18];
  float* out = (float*)d_out;

  const size_t need_f32 = (size_t)T_ * B_ * 512 * sizeof(float);   // 256 MiB
  const int nblk_feat = NBT / 8;   // 16384

  if (ws_size >= need_f32) {
    k_features<0><<<nblk_feat, 256, 0, stream>>>(states, c1w, c1b, c2w, c2b, gfw, gfb,
                                                 cfw, cfb, tw, tbv, wih, bih, d_ws);
    k_lstm<0><<<B_/4, 256, 0, stream>>>(d_ws, whh, actions, aw, ab, cw, cb, out);
  } else {
    // bf16 gates_x fallback (134 MiB)
    k_features<1><<<nblk_feat, 256, 0, stream>>>(states, c1w, c1b, c2w, c2b, gfw, gfb,
                                                 cfw, cfb, tw, tbv, wih, bih, d_ws);
    k_lstm<1><<<B_/4, 256, 0, stream>>>(d_ws, whh, actions, aw, ab, cw, cb, out);
  }
}

// Round 2
// 2378.908 us; speedup vs baseline: 3.5633x; 3.5633x over previous
//
#include <hip/hip_runtime.h>
#include <hip/hip_bf16.h>

typedef unsigned int  u32;
typedef unsigned short u16;
typedef __attribute__((ext_vector_type(8))) short bf16x8;
typedef __attribute__((ext_vector_type(4))) float f32x4;

#define B_   1024
#define T_   128
#define NBT  (B_*T_)

// ---- ws layout (u16 element offsets from base) ----
#define WG_OFF   0          // grid_fc  [128][2240] bf16
#define WT_OFF   286720     // trunk    [128][192]  bf16
#define WIH_OFF  311296     // W_ih     [512][128]  bf16
#define W2_OFF   376832     // conv2    [32][160]   bf16 (tap-pair layout, tap9=0)
#define CVT_TOTAL 381952
#define GATES_BYTE_OFF (1u<<20)

__device__ __forceinline__ float bf_lo(u32 u){ return __uint_as_float(u << 16); }
__device__ __forceinline__ float bf_hi(u32 u){ return __uint_as_float(u & 0xffff0000u); }
__device__ __forceinline__ u16 f2bf(float f){
  u32 u = __float_as_uint(f);
  u32 r = u + 0x7fffu + ((u >> 16) & 1u);   // RNE
  return (u16)(r >> 16);
}

// ---------------------------------------------------------------------------
// K0: convert weights to bf16 into workspace (incl. conv2 tap-pair reindex)
// ---------------------------------------------------------------------------
__global__ void k_cvt(const float* __restrict__ gfw, const float* __restrict__ tw,
                      const float* __restrict__ wih, const float* __restrict__ c2w,
                      u16* __restrict__ wsb) {
  int i = blockIdx.x * 256 + threadIdx.x;
  if (i >= CVT_TOTAL) return;
  float v;
  if (i < WT_OFF)        v = gfw[i];
  else if (i < WIH_OFF)  v = tw[i - WT_OFF];
  else if (i < W2_OFF)   v = wih[i - WIH_OFF];
  else {
    int j = i - W2_OFF; int co = j / 160; int k = j - co*160;
    int tap = k >> 4; int ci = k & 15;
    v = (tap < 9) ? c2w[co*144 + ci*9 + tap] : 0.f;
  }
  wsb[i] = f2bf(v);
}

// ---------------------------------------------------------------------------
// K1: MFMA feature pipeline. 16 samples/block, 512 threads (8 waves).
// conv1 (VALU, zero-halo bf16) -> conv2 (5x K=32 tap-pair MFMA, M=1120)
// -> grid_fc (K=2240 MFMA, K-split over 8 waves + LDS reduce)
// -> ctx_fc (VALU) -> trunk (K=192 MFMA) -> W_ih (N=512 MFMA) -> gates_x.
// ---------------------------------------------------------------------------
template<int USE_BF16>
__global__ __launch_bounds__(512, 2) void k_features(
    const float* __restrict__ states,
    const float* __restrict__ c1w, const float* __restrict__ c1b,
    const float* __restrict__ c2b,
    const float* __restrict__ gfb,
    const float* __restrict__ cfw, const float* __restrict__ cfb,
    const float* __restrict__ tbv,
    const float* __restrict__ bih,
    const u16* __restrict__ wsb,
    void* __restrict__ gates_out)
{
  // act1 halo tile [16][108][16] bf16 (55296 B)  /  grid_fc partials [8][16][128] f32 (65536 B)
  __shared__ __align__(16) u32 s_u[16384];                 // 64 KB union
  __shared__ __align__(16) u16 s_c2[16][2248];             // 71.9 KB (pad: 4496 B row = 4 mod 32 banks)
  __shared__ float s_st[16][96];                           // 6 KB
  __shared__ __align__(16) u16 s_tr[16][200];              // 6.4 KB (400 B row)
  __shared__ __align__(16) u16 s_h0[16][136];              // 4.3 KB (272 B row)
  __shared__ float s_w1[144];
  __shared__ float s_c1b[16];

  u16*   act1   = (u16*)s_u;
  float* s_part = (float*)s_u;

  const int tid  = threadIdx.x;
  const int lane = tid & 63;
  const int w    = tid >> 6;        // wave 0..7
  const int arow = lane & 15;
  const int grp  = lane >> 4;       // 0..3
  const int n0   = blockIdx.x * 16;

  // ---- stage ----
  for (int i = tid; i < 16*94; i += 512) {
    int s = i / 94; int c = i - s*94;
    s_st[s][c] = states[(size_t)n0*94 + i];
  }
  for (int i = tid; i < 144; i += 512) s_w1[i] = c1w[i];
  if (tid < 16) s_c1b[tid] = c1b[tid];
  // zero halo of act1 (u32 = 2 ch)
  for (int i = tid; i < 16*108*8; i += 512) {
    int s = i / 864; int r = i - s*864; int hp = r >> 3;
    int y = hp / 12; int x = hp - y*12;
    if (y == 0 || y == 8 || x == 0 || x == 11) ((u32*)act1)[i] = 0u;
  }
  __syncthreads();

  // ---- conv1 (VALU) + ctx_fc ----
  for (int i = tid; i < 16*16*70; i += 512) {
    int s = i / 1120; int r = i - s*1120;
    int ch = r / 70;  int p = r - ch*70;
    int y = p / 10,   x = p - y*10;
    float acc = s_c1b[ch];
    #pragma unroll
    for (int dy = 0; dy < 3; dy++) {
      int yy = y + dy - 1;
      if (yy < 0 || yy >= 7) continue;
      #pragma unroll
      for (int dx = 0; dx < 3; dx++) {
        int xx = x + dx - 1;
        if (xx < 0 || xx >= 10) continue;
        acc = fmaf(s_w1[ch*9 + dy*3 + dx], s_st[s][yy*10 + xx], acc);
      }
    }
    act1[(s*108 + (y+1)*12 + (x+1))*16 + ch] = f2bf(fmaxf(acc, 0.f));
  }
  // ctx_fc: 16 s x 64 o, K=24 (VALU) -> s_tr cols 128..191
  for (int i = tid; i < 1024; i += 512) {
    int s = i >> 6, o = i & 63;
    float a = cfb[o];
    #pragma unroll
    for (int k = 0; k < 24; k++) a = fmaf(cfw[o*24 + k], s_st[s][70 + k], a);
    s_tr[s][128 + o] = f2bf(fmaxf(a, 0.f));
  }
  __syncthreads();

  // ---- conv2 MFMA: M=1120 (70 tiles), N=32 (2 tiles), K=160 (5 steps) ----
  {
    bf16x8 b2[5][2];
    const u16* w2p = wsb + W2_OFF;
    #pragma unroll
    for (int p = 0; p < 5; p++)
      #pragma unroll
      for (int nt = 0; nt < 2; nt++)
        b2[p][nt] = *(const bf16x8*)(w2p + (nt*16 + arow)*160 + p*32 + grp*8);

    const float c2b0 = c2b[arow], c2b1 = c2b[16 + arow];
    const int gh  = grp >> 1;
    const int ci0 = (grp & 1) * 8;

    for (int mt = w; mt < 70; mt += 8) {
      int m = mt*16 + arow;
      int s = (int)(((u32)m * 59919u) >> 22); int pos = m - s*70;
      int y = (int)(((u32)pos * 6554u) >> 16); int x = pos - y*10;
      f32x4 acc0 = {0.f,0.f,0.f,0.f}, acc1 = {0.f,0.f,0.f,0.f};
      #pragma unroll
      for (int p = 0; p < 5; p++) {
        int tap = p*2 + gh; if (tap > 8) tap = 8;        // pair 4 upper half: B=0
        int dy = (tap * 11) >> 5; int dx = tap - dy*3;
        int hp = (y + dy)*12 + (x + dx);
        bf16x8 av = *(const bf16x8*)&act1[(s*108 + hp)*16 + ci0];
        acc0 = __builtin_amdgcn_mfma_f32_16x16x32_bf16(av, b2[p][0], acc0, 0, 0, 0);
        acc1 = __builtin_amdgcn_mfma_f32_16x16x32_bf16(av, b2[p][1], acc1, 0, 0, 0);
      }
      #pragma unroll
      for (int r = 0; r < 4; r++) {
        int m2 = mt*16 + grp*4 + r;
        int s2 = (int)(((u32)m2 * 59919u) >> 22); int pos2 = m2 - s2*70;
        s_c2[s2][arow*70 + pos2]        = f2bf(fmaxf(acc0[r] + c2b0, 0.f));
        s_c2[s2][(16 + arow)*70 + pos2] = f2bf(fmaxf(acc1[r] + c2b1, 0.f));
      }
    }
  }
  __syncthreads();

  // ---- grid_fc MFMA: M=16, N=128 (8 tiles), K=2240 (70 steps, K-split by wave) ----
  {
    f32x4 gacc[8];
    #pragma unroll
    for (int nt = 0; nt < 8; nt++) gacc[nt] = (f32x4){0.f,0.f,0.f,0.f};
    const u16* wgp = wsb + WG_OFF;
    for (int ks = w; ks < 70; ks += 8) {
      int k = ks*32 + grp*8;
      bf16x8 av = *(const bf16x8*)&s_c2[arow][k];
      #pragma unroll
      for (int nt = 0; nt < 8; nt++) {
        bf16x8 bv = *(const bf16x8*)(wgp + (nt*16 + arow)*2240 + k);
        gacc[nt] = __builtin_amdgcn_mfma_f32_16x16x32_bf16(av, bv, gacc[nt], 0, 0, 0);
      }
    }
    #pragma unroll
    for (int nt = 0; nt < 8; nt++)
      #pragma unroll
      for (int r = 0; r < 4; r++)
        s_part[(w*16 + grp*4 + r)*128 + nt*16 + arow] = gacc[nt][r];
  }
  __syncthreads();

  // ---- reduce partials + bias + relu -> s_tr[.][0..127] ----
  for (int i = tid; i < 2048; i += 512) {
    int s = i >> 7, o = i & 127;
    float a = gfb[o];
    #pragma unroll
    for (int ww = 0; ww < 8; ww++) a += s_part[(ww*16 + s)*128 + o];
    s_tr[s][o] = f2bf(fmaxf(a, 0.f));
  }
  __syncthreads();

  // ---- trunk MFMA: M=16, N=128 (wave=1 tile), K=192 (6 steps) ----
  {
    f32x4 tacc = {0.f,0.f,0.f,0.f};
    const u16* wtp = wsb + WT_OFF;
    #pragma unroll
    for (int ks = 0; ks < 6; ks++) {
      int k = ks*32 + grp*8;
      bf16x8 av = *(const bf16x8*)&s_tr[arow][k];
      bf16x8 bv = *(const bf16x8*)(wtp + (w*16 + arow)*192 + k);
      tacc = __builtin_amdgcn_mfma_f32_16x16x32_bf16(av, bv, tacc, 0, 0, 0);
    }
    int o = w*16 + arow;
    float bv = tbv[o];
    #pragma unroll
    for (int r = 0; r < 4; r++) {
      int s = grp*4 + r;
      s_h0[s][o] = f2bf(fmaxf(tacc[r] + bv, 0.f));
    }
  }
  __syncthreads();

  // ---- W_ih MFMA: M=16, N=512 (wave=4 tiles), K=128 (4 steps) -> gates_x ----
  {
    f32x4 hacc[4];
    #pragma unroll
    for (int j = 0; j < 4; j++) hacc[j] = (f32x4){0.f,0.f,0.f,0.f};
    const u16* wip = wsb + WIH_OFF;
    #pragma unroll
    for (int ks = 0; ks < 4; ks++) {
      int k = ks*32 + grp*8;
      bf16x8 av = *(const bf16x8*)&s_h0[arow][k];
      #pragma unroll
      for (int j = 0; j < 4; j++) {
        bf16x8 bv = *(const bf16x8*)(wip + ((w*4 + j)*16 + arow)*128 + k);
        hacc[j] = __builtin_amdgcn_mfma_f32_16x16x32_bf16(av, bv, hacc[j], 0, 0, 0);
      }
    }
    #pragma unroll
    for (int j = 0; j < 4; j++) {
      int gate = w*64 + j*16 + arow;
      float bv = bih[gate];
      #pragma unroll
      for (int r = 0; r < 4; r++) {
        int s = grp*4 + r;
        int n = n0 + s; int tt = n & 127; int bb = n >> 7;
        size_t off = ((size_t)tt * B_ + bb) * 512 + gate;
        float v = hacc[j][r] + bv;
        if (USE_BF16) ((u16*)gates_out)[off] = f2bf(v);
        else          ((float*)gates_out)[off] = v;
      }
    }
  }
}

// ---------------------------------------------------------------------------
// K2: LSTM over T=128 + fused heads (unchanged from R1; 4 batch rows/block).
// ---------------------------------------------------------------------------
template<int USE_BF16>
__global__ __launch_bounds__(256, 1) void k_lstm(
    const void* __restrict__ gates_x, const float* __restrict__ whh,
    const int* __restrict__ actions,
    const float* __restrict__ aw, const float* __restrict__ ab,
    const float* __restrict__ cw, const float* __restrict__ cb,
    float* __restrict__ out)
{
  __shared__ u16   s_WT[128][512];   // WT[k][g] = W_hh[g][k], bf16
  __shared__ float s_h[4][128];
  __shared__ float s_g[4][512];

  const int tid = threadIdx.x;
  const int b0  = blockIdx.x * 4;

  for (int i = tid; i < 512*128; i += 256) {
    int g = i >> 7, k = i & 127;
    s_WT[k][g] = f2bf(whh[i]);
  }
  for (int i = tid; i < 512; i += 256) s_h[i >> 7][i & 127] = 0.f;

  const int gb  = tid >> 6;
  const int gg0 = (tid & 63) * 8;
  const int eb  = tid >> 6;
  const int eh  = tid & 63;

  float creg0 = 0.f, creg1 = 0.f;
  float haw[4][2], hcw[2];
  #pragma unroll
  for (int j = 0; j < 4; j++) { haw[j][0] = aw[j*128 + eh]; haw[j][1] = aw[j*128 + eh + 64]; }
  hcw[0] = cw[eh]; hcw[1] = cw[eh + 64];
  const float ab0 = ab[0], ab1 = ab[1], ab2 = ab[2], ab3 = ab[3], cb0 = cb[0];

  __syncthreads();

  for (int t = 0; t < T_; t++) {
    float acc[8];
    size_t gxoff = ((size_t)t * B_ + (b0 + gb)) * 512 + gg0;
    if (USE_BF16) {
      uint4 gv = *(const uint4*)((const u16*)gates_x + gxoff);
      acc[0]=bf_lo(gv.x); acc[1]=bf_hi(gv.x); acc[2]=bf_lo(gv.y); acc[3]=bf_hi(gv.y);
      acc[4]=bf_lo(gv.z); acc[5]=bf_hi(gv.z); acc[6]=bf_lo(gv.w); acc[7]=bf_hi(gv.w);
    } else {
      float4 g0 = *(const float4*)((const float*)gates_x + gxoff);
      float4 g1 = *(const float4*)((const float*)gates_x + gxoff + 4);
      acc[0]=g0.x; acc[1]=g0.y; acc[2]=g0.z; acc[3]=g0.w;
      acc[4]=g1.x; acc[5]=g1.y; acc[6]=g1.z; acc[7]=g1.w;
    }
    for (int k = 0; k < 128; k += 4) {
      float4 h4 = *(const float4*)&s_h[gb][k];
      #pragma unroll
      for (int j = 0; j < 4; j++) {
        float hv = (&h4.x)[j];
        uint4 wv = *(const uint4*)&s_WT[k + j][gg0];
        acc[0] = fmaf(bf_lo(wv.x), hv, acc[0]);
        acc[1] = fmaf(bf_hi(wv.x), hv, acc[1]);
        acc[2] = fmaf(bf_lo(wv.y), hv, acc[2]);
        acc[3] = fmaf(bf_hi(wv.y), hv, acc[3]);
        acc[4] = fmaf(bf_lo(wv.z), hv, acc[4]);
        acc[5] = fmaf(bf_hi(wv.z), hv, acc[5]);
        acc[6] = fmaf(bf_lo(wv.w), hv, acc[6]);
        acc[7] = fmaf(bf_hi(wv.w), hv, acc[7]);
      }
    }
    #pragma unroll
    for (int j = 0; j < 8; j++) s_g[gb][gg0 + j] = acc[j];
    __syncthreads();

    float hn0, hn1;
    {
      float iv = s_g[eb][eh];
      float fv = s_g[eb][eh + 128];
      float gv = s_g[eb][eh + 256];
      float ov = s_g[eb][eh + 384];
      iv = 1.f / (1.f + __expf(-iv));
      fv = 1.f / (1.f + __expf(-fv));
      ov = 1.f / (1.f + __expf(-ov));
      gv = tanhf(gv);
      creg0 = fv * creg0 + iv * gv;
      hn0 = ov * tanhf(creg0);
      s_h[eb][eh] = hn0;
    }
    {
      float iv = s_g[eb][eh + 64];
      float fv = s_g[eb][eh + 64 + 128];
      float gv = s_g[eb][eh + 64 + 256];
      float ov = s_g[eb][eh + 64 + 384];
      iv = 1.f / (1.f + __expf(-iv));
      fv = 1.f / (1.f + __expf(-fv));
      ov = 1.f / (1.f + __expf(-ov));
      gv = tanhf(gv);
      creg1 = fv * creg1 + iv * gv;
      hn1 = ov * tanhf(creg1);
      s_h[eb][eh + 64] = hn1;
    }
    __syncthreads();

    float l0 = hn0*haw[0][0] + hn1*haw[0][1];
    float l1 = hn0*haw[1][0] + hn1*haw[1][1];
    float l2 = hn0*haw[2][0] + hn1*haw[2][1];
    float l3 = hn0*haw[3][0] + hn1*haw[3][1];
    float lv = hn0*hcw[0]    + hn1*hcw[1];
    #pragma unroll
    for (int off = 32; off; off >>= 1) {
      l0 += __shfl_xor(l0, off); l1 += __shfl_xor(l1, off);
      l2 += __shfl_xor(l2, off); l3 += __shfl_xor(l3, off);
      lv += __shfl_xor(lv, off);
    }
    if (eh == 0) {
      l0 += ab0; l1 += ab1; l2 += ab2; l3 += ab3; lv += cb0;
      float m  = fmaxf(fmaxf(l0, l1), fmaxf(l2, l3));
      float e0 = __expf(l0 - m), e1 = __expf(l1 - m), e2 = __expf(l2 - m), e3 = __expf(l3 - m);
      float S  = e0 + e1 + e2 + e3;
      float lse = __logf(S);
      float p0 = l0 - m - lse, p1 = l1 - m - lse, p2 = l2 - m - lse, p3 = l3 - m - lse;
      int n = (b0 + eb) * T_ + t;
      int a = actions[n];
      float lpa = (a == 0) ? p0 : (a == 1) ? p1 : (a == 2) ? p2 : p3;
      float ent = -(e0*p0 + e1*p1 + e2*p2 + e3*p3) / S;
      out[n]           = lpa;
      out[NBT + n]     = lv;
      out[2*NBT + n]   = ent;
    }
  }
}

extern "C" void kernel_launch(void* const* d_in, const int* in_sizes, int n_in,
                              void* d_out, int out_size, void* d_ws, size_t ws_size,
                              hipStream_t stream) {
  const float* states = (const float*)d_in[0];
  const int*   actions= (const int*)  d_in[1];
  const float* c1w = (const float*)d_in[2];
  const float* c1b = (const float*)d_in[3];
  const float* c2w = (const float*)d_in[4];
  const float* c2b = (const float*)d_in[5];
  const float* gfw = (const float*)d_in[6];
  const float* gfb = (const float*)d_in[7];
  const float* cfw = (const float*)d_in[8];
  const float* cfb = (const float*)d_in[9];
  const float* tw  = (const float*)d_in[10];
  const float* tbv = (const float*)d_in[11];
  const float* wih = (const float*)d_in[12];
  const float* bih = (const float*)d_in[13];
  const float* whh = (const float*)d_in[14];
  const float* aw  = (const float*)d_in[15];
  const float* ab  = (const float*)d_in[16];
  const float* cw  = (const float*)d_in[17];
  const float* cb  = (const float*)d_in[18];
  float* out = (float*)d_out;

  u16*  wsb   = (u16*)d_ws;
  void* gates = (void*)((char*)d_ws + GATES_BYTE_OFF);

  k_cvt<<<(CVT_TOTAL + 255)/256, 256, 0, stream>>>(gfw, tw, wih, c2w, wsb);

  const size_t need_f32 = GATES_BYTE_OFF + (size_t)T_ * B_ * 512 * sizeof(float);
  const int nblk_feat = NBT / 16;   // 8192

  if (ws_size >= need_f32) {
    k_features<0><<<nblk_feat, 512, 0, stream>>>(states, c1w, c1b, c2b, gfb,
                                                 cfw, cfb, tbv, bih, wsb, gates);
    k_lstm<0><<<B_/4, 256, 0, stream>>>(gates, whh, actions, aw, ab, cw, cb, out);
  } else {
    k_features<1><<<nblk_feat, 512, 0, stream>>>(states, c1w, c1b, c2b, gfb,
                                                 cfw, cfb, tbv, bih, wsb, gates);
    k_lstm<1><<<B_/4, 256, 0, stream>>>(gates, whh, actions, aw, ab, cw, cb, out);
  }
}

// Round 4
// 1668.913 us; speedup vs baseline: 5.0793x; 1.4254x over previous
//
#include <hip/hip_runtime.h>
#include <hip/hip_bf16.h>

typedef unsigned int  u32;
typedef unsigned short u16;
typedef unsigned long long u64;
typedef __attribute__((ext_vector_type(8))) short bf16x8;
typedef __attribute__((ext_vector_type(4))) float f32x4;

#define B_   1024
#define T_   128
#define NBT  (B_*T_)

// ---- ws layout (u16 element offsets) ----
#define WG_OFF   0          // grid_fc [128][2240] bf16
#define WT_OFF   286720     // trunk   [128][192]  bf16
#define WIH_OFF  311296     // W_ih    [512][128]  bf16
#define W2_OFF   376832     // conv2   [32][160]   bf16 (tap-pair, tap9=0)
#define CVT_TOTAL 381952
#define GATES_BYTE_OFF (1u<<20)

__device__ __forceinline__ u16 f2bf(float f){
  u32 u = __float_as_uint(f);
  u32 r = u + 0x7fffu + ((u >> 16) & 1u);   // RNE
  return (u16)(r >> 16);
}
__device__ __forceinline__ float sigm(float x){ return 1.f / (1.f + __expf(-x)); }
__device__ __forceinline__ float tanh_f(float x){ return 2.f / (1.f + __expf(-2.f*x)) - 1.f; }

// ---------------------------------------------------------------------------
// K0: weights -> bf16 workspace
// ---------------------------------------------------------------------------
__global__ void k_cvt(const float* __restrict__ gfw, const float* __restrict__ tw,
                      const float* __restrict__ wih, const float* __restrict__ c2w,
                      u16* __restrict__ wsb) {
  int i = blockIdx.x * 256 + threadIdx.x;
  if (i >= CVT_TOTAL) return;
  float v;
  if (i < WT_OFF)        v = gfw[i];
  else if (i < WIH_OFF)  v = tw[i - WT_OFF];
  else if (i < W2_OFF)   v = wih[i - WIH_OFF];
  else {
    int j = i - W2_OFF; int co = j / 160; int k = j - co*160;
    int tap = k >> 4; int ci = k & 15;
    v = (tap < 9) ? c2w[co*144 + ci*9 + tap] : 0.f;
  }
  wsb[i] = f2bf(v);
}

// ---------------------------------------------------------------------------
// K1: feature pipeline, 16 samples / 1024 threads (16 waves).
// ---------------------------------------------------------------------------
__global__ __launch_bounds__(1024, 1) void k_features(
    const float* __restrict__ states,
    const float* __restrict__ c1w, const float* __restrict__ c1b,
    const float* __restrict__ c2b, const float* __restrict__ gfb,
    const float* __restrict__ cfw, const float* __restrict__ cfb,
    const float* __restrict__ tbv, const float* __restrict__ bih,
    const u16* __restrict__ wsb, u16* __restrict__ gates_out)
{
  __shared__ __align__(16) u32 s_u[13824];          // act1 [16][108][16]u16  UNION  p_buf [2][16][132]f32
  __shared__ __align__(16) u16 s_c2[16][2248];      // 71.9 KB
  __shared__ float s_st[16][96];
  __shared__ __align__(16) u16 s_tr[16][200];
  __shared__ __align__(16) u16 s_h0[16][136];
  __shared__ float s_w1[144];
  __shared__ float s_c1b[16];

  u16*   act1  = (u16*)s_u;
  float* p_buf = (float*)s_u;   // [2][16][132]

  const int tid  = threadIdx.x;
  const int lane = tid & 63;
  const int w    = tid >> 6;        // 0..15
  const int arow = lane & 15;
  const int grp  = lane >> 4;
  const int n0   = blockIdx.x * 16;

  // ---- stage ----
  for (int i = tid; i < 16*94; i += 1024) {
    int s = i / 94; int c = i - s*94;
    s_st[s][c] = states[(size_t)n0*94 + i];
  }
  if (tid < 144) s_w1[tid] = c1w[tid];
  if (tid >= 192 && tid < 208) s_c1b[tid-192] = c1b[tid-192];
  for (int i = tid; i < 13824; i += 1024) s_u[i] = 0u;   // zero act1 (incl. halo)
  __syncthreads();

  // ---- conv1 (VALU) + ctx_fc ----
  for (int i = tid; i < 16*16*70; i += 1024) {
    int s = i / 1120; int r = i - s*1120;
    int ch = r / 70;  int p = r - ch*70;
    int y = p / 10,   x = p - y*10;
    float acc = s_c1b[ch];
    #pragma unroll
    for (int dy = 0; dy < 3; dy++) {
      int yy = y + dy - 1;
      if (yy < 0 || yy >= 7) continue;
      #pragma unroll
      for (int dx = 0; dx < 3; dx++) {
        int xx = x + dx - 1;
        if (xx < 0 || xx >= 10) continue;
        acc = fmaf(s_w1[ch*9 + dy*3 + dx], s_st[s][yy*10 + xx], acc);
      }
    }
    act1[(s*108 + (y+1)*12 + (x+1))*16 + ch] = f2bf(fmaxf(acc, 0.f));
  }
  {
    int s = tid >> 6, o = tid & 63;   // 1024 threads = 16x64 exactly
    float a = cfb[o];
    #pragma unroll
    for (int k = 0; k < 24; k++) a = fmaf(cfw[o*24 + k], s_st[s][70 + k], a);
    s_tr[s][128 + o] = f2bf(fmaxf(a, 0.f));
  }
  __syncthreads();

  // ---- conv2 MFMA: M=1120 (70 tiles), N=32, K=160 ----
  {
    bf16x8 b2[5][2];
    const u16* w2p = wsb + W2_OFF;
    #pragma unroll
    for (int p = 0; p < 5; p++)
      #pragma unroll
      for (int nt = 0; nt < 2; nt++)
        b2[p][nt] = *(const bf16x8*)(w2p + (nt*16 + arow)*160 + p*32 + grp*8);

    const float c2b0 = c2b[arow], c2b1 = c2b[16 + arow];
    const int gh  = grp >> 1;
    const int ci0 = (grp & 1) * 8;

    for (int mt = w; mt < 70; mt += 16) {
      int m = mt*16 + arow;
      int s = (int)(((u32)m * 59919u) >> 22); int pos = m - s*70;
      int y = (int)(((u32)pos * 6554u) >> 16); int x = pos - y*10;
      f32x4 acc0 = {0.f,0.f,0.f,0.f}, acc1 = {0.f,0.f,0.f,0.f};
      #pragma unroll
      for (int p = 0; p < 5; p++) {
        int tap = p*2 + gh; if (tap > 8) tap = 8;
        int dy = (tap * 11) >> 5; int dx = tap - dy*3;
        int hp = (y + dy)*12 + (x + dx);
        bf16x8 av = *(const bf16x8*)&act1[(s*108 + hp)*16 + ci0];
        acc0 = __builtin_amdgcn_mfma_f32_16x16x32_bf16(av, b2[p][0], acc0, 0, 0, 0);
        acc1 = __builtin_amdgcn_mfma_f32_16x16x32_bf16(av, b2[p][1], acc1, 0, 0, 0);
      }
      #pragma unroll
      for (int r = 0; r < 4; r++) {
        int m2 = mt*16 + grp*4 + r;
        int s2 = (int)(((u32)m2 * 59919u) >> 22); int pos2 = m2 - s2*70;
        s_c2[s2][arow*70 + pos2]        = f2bf(fmaxf(acc0[r] + c2b0, 0.f));
        s_c2[s2][(16 + arow)*70 + pos2] = f2bf(fmaxf(acc1[r] + c2b1, 0.f));
      }
    }
  }
  __syncthreads();

  // ---- grid_fc MFMA: N-split (wave&7 -> nt), K halved (wave>>3) ----
  {
    const int nt = w & 7, kh = w >> 3;
    const int ksb = kh ? 36 : 0, kse = kh ? 70 : 36;
    const u16* bp = wsb + WG_OFF + (size_t)(nt*16 + arow)*2240 + grp*8;
    const u16* ap = &s_c2[arow][grp*8];
    f32x4 acc0 = {0.f,0.f,0.f,0.f}, acc1 = {0.f,0.f,0.f,0.f};
    for (int ks = ksb; ks < kse; ks += 2) {
      bf16x8 a0 = *(const bf16x8*)(ap + ks*32);
      bf16x8 b0 = *(const bf16x8*)(bp + (size_t)ks*32);
      bf16x8 a1 = *(const bf16x8*)(ap + ks*32 + 32);
      bf16x8 b1 = *(const bf16x8*)(bp + (size_t)ks*32 + 32);
      acc0 = __builtin_amdgcn_mfma_f32_16x16x32_bf16(a0, b0, acc0, 0, 0, 0);
      acc1 = __builtin_amdgcn_mfma_f32_16x16x32_bf16(a1, b1, acc1, 0, 0, 0);
    }
    #pragma unroll
    for (int r = 0; r < 4; r++)
      p_buf[(kh*16 + grp*4 + r)*132 + nt*16 + arow] = acc0[r] + acc1[r];
  }
  __syncthreads();

  // ---- reduce halves + bias + relu ----
  for (int i = tid; i < 2048; i += 1024) {
    int s = i >> 7, o = i & 127;
    float a = p_buf[s*132 + o] + p_buf[(16 + s)*132 + o] + gfb[o];
    s_tr[s][o] = f2bf(fmaxf(a, 0.f));
  }
  __syncthreads();

  // ---- trunk MFMA: waves 0..7, nt=w, K=192 ----
  if (w < 8) {
    f32x4 tacc = {0.f,0.f,0.f,0.f};
    const u16* wtp = wsb + WT_OFF;
    #pragma unroll
    for (int ks = 0; ks < 6; ks++) {
      int k = ks*32 + grp*8;
      bf16x8 av = *(const bf16x8*)&s_tr[arow][k];
      bf16x8 bv = *(const bf16x8*)(wtp + (w*16 + arow)*192 + k);
      tacc = __builtin_amdgcn_mfma_f32_16x16x32_bf16(av, bv, tacc, 0, 0, 0);
    }
    int o = w*16 + arow;
    float bv = tbv[o];
    #pragma unroll
    for (int r = 0; r < 4; r++) {
      int s = grp*4 + r;
      s_h0[s][o] = f2bf(fmaxf(tacc[r] + bv, 0.f));
    }
  }
  __syncthreads();

  // ---- W_ih MFMA: 32 gate-tiles, wave -> 2 tiles ----
  {
    const u16* wip = wsb + WIH_OFF;
    #pragma unroll
    for (int jj = 0; jj < 2; jj++) {
      int j = w*2 + jj;
      f32x4 hacc = {0.f,0.f,0.f,0.f};
      #pragma unroll
      for (int ks = 0; ks < 4; ks++) {
        int k = ks*32 + grp*8;
        bf16x8 av = *(const bf16x8*)&s_h0[arow][k];
        bf16x8 bv = *(const bf16x8*)(wip + (j*16 + arow)*128 + k);
        hacc = __builtin_amdgcn_mfma_f32_16x16x32_bf16(av, bv, hacc, 0, 0, 0);
      }
      int gate = j*16 + arow;
      float bvv = bih[gate];
      #pragma unroll
      for (int r = 0; r < 4; r++) {
        int s = grp*4 + r;
        int n = n0 + s; int tt = n & 127; int bb = n >> 7;
        gates_out[((size_t)tt * B_ + bb) * 512 + gate] = f2bf(hacc[r] + bvv);
      }
    }
  }
}

// ---------------------------------------------------------------------------
// K2: MFMA LSTM. 64 blocks x 16 batch rows x 512 threads (8 waves).
// W_hh fragments live in registers; gates_x prefetched 1 step ahead.
// FIX vs R3: stage/prefetch the FULL 16x512 tile (16 u16/thread, was 8).
// ---------------------------------------------------------------------------
__global__ __launch_bounds__(512, 1) void k_lstm(
    const u16* __restrict__ gates_x, const float* __restrict__ whh,
    const int* __restrict__ actions,
    const float* __restrict__ aw, const float* __restrict__ ab,
    const float* __restrict__ cw, const float* __restrict__ cb,
    float* __restrict__ out)
{
  __shared__ __align__(16) u16  s_gx[2][16*512];    // 32 KB double-buffered gates_x tile
  __shared__ __align__(16) float s_g[16*524];       // 33.5 KB MFMA gate output (pad 524)
  __shared__ __align__(16) u16  s_h[16*136];        // h bf16 (pad 136)
  __shared__ int s_act[2048];

  const int tid  = threadIdx.x;
  const int lane = tid & 63;
  const int w    = tid >> 6;
  const int arow = lane & 15;
  const int grp  = lane >> 4;
  const int b0   = blockIdx.x * 16;

  // ---- W_hh B-fragments in registers: rows (w*4+j)*16+arow ----
  bf16x8 Bv[4][4];
  #pragma unroll
  for (int j = 0; j < 4; j++)
    #pragma unroll
    for (int ks = 0; ks < 4; ks++) {
      const float* src = whh + (size_t)((w*4 + j)*16 + arow)*128 + ks*32 + grp*8;
      float4 x0 = *(const float4*)src;
      float4 x1 = *(const float4*)(src + 4);
      bf16x8 tv;
      tv[0]=(short)f2bf(x0.x); tv[1]=(short)f2bf(x0.y); tv[2]=(short)f2bf(x0.z); tv[3]=(short)f2bf(x0.w);
      tv[4]=(short)f2bf(x1.x); tv[5]=(short)f2bf(x1.y); tv[6]=(short)f2bf(x1.z); tv[7]=(short)f2bf(x1.w);
      Bv[j][ks] = tv;
    }

  for (int i = tid; i < 16*136; i += 512) s_h[i] = 0;
  for (int i = tid; i < 2048; i += 512) s_act[i] = actions[b0*T_ + i];

  const int es  = tid >> 5;          // sample 0..15
  const int eh0 = (tid & 31) * 4;    // 4 h-cells per thread
  float haw[4][4], hcwv[4];
  #pragma unroll
  for (int j = 0; j < 4; j++)
    #pragma unroll
    for (int c = 0; c < 4; c++) haw[j][c] = aw[j*128 + eh0 + c];
  #pragma unroll
  for (int c = 0; c < 4; c++) hcwv[c] = cw[eh0 + c];
  const float ab0=ab[0], ab1=ab[1], ab2=ab[2], ab3=ab[3], cb0=cb[0];
  float cst[4] = {0.f,0.f,0.f,0.f};

  // stage t=0: full tile, 512 threads x 16 u16
  {
    const u16* src = gates_x + (size_t)b0*512 + tid*16;
    uint4 v0 = *(const uint4*)src;
    uint4 v1 = *(const uint4*)(src + 8);
    *(uint4*)&s_gx[0][tid*16]     = v0;
    *(uint4*)&s_gx[0][tid*16 + 8] = v1;
  }
  __syncthreads();

  for (int t = 0; t < T_; t++) {
    // prefetch next gates tile into regs (stays in flight across raw barrier)
    uint4 pre0, pre1;
    const bool haspre = (t + 1 < T_);
    if (haspre) {
      const u16* src = gates_x + ((size_t)(t+1)*B_ + b0)*512 + tid*16;
      pre0 = *(const uint4*)src;
      pre1 = *(const uint4*)(src + 8);
    }

    // ---- MFMA: gates_r = h @ W_hh^T ----
    f32x4 acc[4];
    #pragma unroll
    for (int j = 0; j < 4; j++) acc[j] = (f32x4){0.f,0.f,0.f,0.f};
    #pragma unroll
    for (int ks = 0; ks < 4; ks++) {
      bf16x8 av = *(const bf16x8*)&s_h[arow*136 + ks*32 + grp*8];
      #pragma unroll
      for (int j = 0; j < 4; j++)
        acc[j] = __builtin_amdgcn_mfma_f32_16x16x32_bf16(av, Bv[j][ks], acc[j], 0, 0, 0);
    }
    #pragma unroll
    for (int j = 0; j < 4; j++)
      #pragma unroll
      for (int r = 0; r < 4; r++)
        s_g[(grp*4 + r)*524 + (w*4 + j)*16 + arow] = acc[j][r];

    asm volatile("s_waitcnt lgkmcnt(0)" ::: "memory");
    __builtin_amdgcn_s_barrier();
    __builtin_amdgcn_sched_barrier(0);

    // ---- elementwise LSTM cell (4 cells/thread) + heads ----
    const u16* gx = &s_gx[t & 1][es*512 + eh0];
    u64 gi = *(const u64*)(gx);
    u64 gf = *(const u64*)(gx + 128);
    u64 gg = *(const u64*)(gx + 256);
    u64 go = *(const u64*)(gx + 384);
    float4 si = *(const float4*)&s_g[es*524 + eh0];
    float4 sf = *(const float4*)&s_g[es*524 + eh0 + 128];
    float4 sg = *(const float4*)&s_g[es*524 + eh0 + 256];
    float4 so = *(const float4*)&s_g[es*524 + eh0 + 384];

    float hv[4];
    #pragma unroll
    for (int c = 0; c < 4; c++) {
      float xi = (&si.x)[c] + __uint_as_float((u32)((gi >> (16*c)) & 0xffffu) << 16);
      float xf = (&sf.x)[c] + __uint_as_float((u32)((gf >> (16*c)) & 0xffffu) << 16);
      float xg = (&sg.x)[c] + __uint_as_float((u32)((gg >> (16*c)) & 0xffffu) << 16);
      float xo = (&so.x)[c] + __uint_as_float((u32)((go >> (16*c)) & 0xffffu) << 16);
      float I = sigm(xi), F = sigm(xf), O = sigm(xo), G = tanh_f(xg);
      cst[c] = F*cst[c] + I*G;
      hv[c] = O * tanh_f(cst[c]);
    }
    {
      ushort4 hs;
      hs.x = f2bf(hv[0]); hs.y = f2bf(hv[1]); hs.z = f2bf(hv[2]); hs.w = f2bf(hv[3]);
      *(ushort4*)&s_h[es*136 + eh0] = hs;
    }

    float l0 = hv[0]*haw[0][0] + hv[1]*haw[0][1] + hv[2]*haw[0][2] + hv[3]*haw[0][3];
    float l1 = hv[0]*haw[1][0] + hv[1]*haw[1][1] + hv[2]*haw[1][2] + hv[3]*haw[1][3];
    float l2 = hv[0]*haw[2][0] + hv[1]*haw[2][1] + hv[2]*haw[2][2] + hv[3]*haw[2][3];
    float l3 = hv[0]*haw[3][0] + hv[1]*haw[3][1] + hv[2]*haw[3][2] + hv[3]*haw[3][3];
    float lv = hv[0]*hcwv[0]   + hv[1]*hcwv[1]   + hv[2]*hcwv[2]   + hv[3]*hcwv[3];
    #pragma unroll
    for (int off = 16; off; off >>= 1) {
      l0 += __shfl_xor(l0, off); l1 += __shfl_xor(l1, off);
      l2 += __shfl_xor(l2, off); l3 += __shfl_xor(l3, off);
      lv += __shfl_xor(lv, off);
    }
    if ((tid & 31) == 0) {
      l0 += ab0; l1 += ab1; l2 += ab2; l3 += ab3; lv += cb0;
      float m  = fmaxf(fmaxf(l0, l1), fmaxf(l2, l3));
      float e0 = __expf(l0 - m), e1 = __expf(l1 - m), e2 = __expf(l2 - m), e3 = __expf(l3 - m);
      float S  = e0 + e1 + e2 + e3;
      float lse = __logf(S);
      float p0 = l0 - m - lse, p1 = l1 - m - lse, p2 = l2 - m - lse, p3 = l3 - m - lse;
      int n = (b0 + es) * T_ + t;
      int a = s_act[es*T_ + t];
      float lpa = (a == 0) ? p0 : (a == 1) ? p1 : (a == 2) ? p2 : p3;
      float ent = -(e0*p0 + e1*p1 + e2*p2 + e3*p3) / S;
      out[n]         = lpa;
      out[NBT + n]   = lv;
      out[2*NBT + n] = ent;
    }

    // park prefetched tile for step t+1 (compiler waits its own vmcnt here)
    if (haspre) {
      *(uint4*)&s_gx[(t+1) & 1][tid*16]     = pre0;
      *(uint4*)&s_gx[(t+1) & 1][tid*16 + 8] = pre1;
    }
    __syncthreads();
  }
}

extern "C" void kernel_launch(void* const* d_in, const int* in_sizes, int n_in,
                              void* d_out, int out_size, void* d_ws, size_t ws_size,
                              hipStream_t stream) {
  const float* states = (const float*)d_in[0];
  const int*   actions= (const int*)  d_in[1];
  const float* c1w = (const float*)d_in[2];
  const float* c1b = (const float*)d_in[3];
  const float* c2w = (const float*)d_in[4];
  const float* c2b = (const float*)d_in[5];
  const float* gfw = (const float*)d_in[6];
  const float* gfb = (const float*)d_in[7];
  const float* cfw = (const float*)d_in[8];
  const float* cfb = (const float*)d_in[9];
  const float* tw  = (const float*)d_in[10];
  const float* tbv = (const float*)d_in[11];
  const float* wih = (const float*)d_in[12];
  const float* bih = (const float*)d_in[13];
  const float* whh = (const float*)d_in[14];
  const float* aw  = (const float*)d_in[15];
  const float* ab  = (const float*)d_in[16];
  const float* cw  = (const float*)d_in[17];
  const float* cb  = (const float*)d_in[18];
  float* out = (float*)d_out;

  u16* wsb   = (u16*)d_ws;
  u16* gates = (u16*)((char*)d_ws + GATES_BYTE_OFF);

  k_cvt<<<(CVT_TOTAL + 255)/256, 256, 0, stream>>>(gfw, tw, wih, c2w, wsb);
  k_features<<<NBT/16, 1024, 0, stream>>>(states, c1w, c1b, c2b, gfb,
                                          cfw, cfb, tbv, bih, wsb, gates);
  k_lstm<<<B_/16, 512, 0, stream>>>(gates, whh, actions, aw, ab, cw, cb, out);
}